// Round 2
// baseline (165.675 us; speedup 1.0000x reference)
//
#include <hip/hip_runtime.h>

// DotMatrix: out[b,i,j, ell*32+tau, c] = complex dot over m of
//   a = rep_ell[b,i,tau,:,:]  and  w[m] = rep_ell[b,j,tau,2ell-m,:] * (-1)^(m-ell)
// Pure HBM-write-bound: 134 MB out, 2 MB in.

namespace {

constexpr int Bn = 2;
constexpr int Nn = 256;
constexpr int TAUn = 32;
constexpr int TI = 16;
constexpr int TJ = 16;
constexpr int OUTPAIR = 2 * 4 * TAUn;  // 256 floats per (b,i,j)

template <int ELL>
__device__ __forceinline__ void dot_ell(const float* __restrict__ rep,
                                        float* __restrict__ out,
                                        int b, int i0, int j0, int tid,
                                        float* lds) {
  constexpr int M = 2 * ELL + 1;
  constexpr int RF = TAUn * M * 2;  // floats per (b,n) row

  // --- stage 16 contiguous A-rows into LDS via float4 ---
  const float4* gA4 = reinterpret_cast<const float4*>(rep + (size_t)(b * Nn + i0) * RF);
  float4* lds4 = reinterpret_cast<float4*>(lds);
  constexpr int N4 = TI * RF / 4;  // 256*M float4s
  for (int k = tid; k < N4; k += 256) lds4[k] = gA4[k];
  __syncthreads();

  // thread -> (j', i'-half, 4 taus)
  const int tausub = tid & 7;   // taus [4*tausub, 4*tausub+4)
  const int slot   = tid >> 3;  // 0..31
  const int jj     = slot & 15; // j'
  const int i0s    = slot >> 4; // 0..1 (i' parity)

  // --- load j-fragment once, apply flip over m and sign; cache in regs ---
  const float* gB = rep + (size_t)(b * Nn + j0 + jj) * RF + tausub * 4 * (2 * M);
  float w[4][M][2];
  #pragma unroll
  for (int q = 0; q < 4; ++q) {
    #pragma unroll
    for (int m = 0; m < M; ++m) {
      const float s = ((m ^ ELL) & 1) ? -1.0f : 1.0f;
      w[q][m][0] = gB[q * 2 * M + (2 * ELL - m) * 2 + 0] * s;
      w[q][m][1] = gB[q * 2 * M + (2 * ELL - m) * 2 + 1] * s;
    }
  }

  // --- loop over 8 i' values (wave-uniform i' => broadcast LDS reads) ---
  #pragma unroll
  for (int it = 0; it < 8; ++it) {
    const int ii = i0s + 2 * it;
    const float* la = lds + ii * RF + tausub * 4 * (2 * M);
    float res[8];
    #pragma unroll
    for (int q = 0; q < 4; ++q) {
      float dr = 0.0f, di = 0.0f;
      #pragma unroll
      for (int m = 0; m < M; ++m) {
        const float ar = la[q * 2 * M + 2 * m];
        const float ai = la[q * 2 * M + 2 * m + 1];
        dr = fmaf(ar, w[q][m][0], dr);
        dr = fmaf(-ai, w[q][m][1], dr);
        di = fmaf(ar, w[q][m][1], di);
        di = fmaf(ai, w[q][m][0], di);
      }
      res[2 * q]     = dr;
      res[2 * q + 1] = di;
    }
    // out offset: pair_base*256 + ELL*64 + tausub*8  (32B-aligned)
    float* op = out + (size_t)((b * Nn + i0 + ii) * Nn + (j0 + jj)) * OUTPAIR
                + ELL * 64 + tausub * 8;
    reinterpret_cast<float4*>(op)[0] = make_float4(res[0], res[1], res[2], res[3]);
    reinterpret_cast<float4*>(op)[1] = make_float4(res[4], res[5], res[6], res[7]);
  }
}

__global__ __launch_bounds__(256) void dotmat_kernel(
    const float* __restrict__ r0, const float* __restrict__ r1,
    const float* __restrict__ r2, const float* __restrict__ r3,
    float* __restrict__ out) {
  __shared__ __align__(16) float lds[TI * TAUn * 7 * 2];  // 28 KB (ell=3 worst case)
  const int bz  = blockIdx.z;   // b*4 + ell
  const int b   = bz >> 2;
  const int ell = bz & 3;
  const int i0  = blockIdx.y * TI;
  const int j0  = blockIdx.x * TJ;
  const int tid = threadIdx.x;
  switch (ell) {
    case 0: dot_ell<0>(r0, out, b, i0, j0, tid, lds); break;
    case 1: dot_ell<1>(r1, out, b, i0, j0, tid, lds); break;
    case 2: dot_ell<2>(r2, out, b, i0, j0, tid, lds); break;
    case 3: dot_ell<3>(r3, out, b, i0, j0, tid, lds); break;
  }
}

}  // namespace

extern "C" void kernel_launch(void* const* d_in, const int* in_sizes, int n_in,
                              void* d_out, int out_size, void* d_ws, size_t ws_size,
                              hipStream_t stream) {
  (void)in_sizes; (void)n_in; (void)out_size; (void)d_ws; (void)ws_size;
  const float* r0 = (const float*)d_in[0];
  const float* r1 = (const float*)d_in[1];
  const float* r2 = (const float*)d_in[2];
  const float* r3 = (const float*)d_in[3];
  float* out = (float*)d_out;
  dim3 grid(Nn / TJ, Nn / TI, Bn * 4);  // (j-tiles, i-tiles, b*4+ell)
  dotmat_kernel<<<grid, 256, 0, stream>>>(r0, r1, r2, r3, out);
}

// Round 4
// 150.825 us; speedup vs baseline: 1.0985x; 1.0985x over previous
//
#include <hip/hip_runtime.h>

// DotMatrix, ell-fused: out[b,i,j, ell*32+tau, c] = complex dot over m of
//   a = rep_ell[b,i,tau,:,:]  and  w[m] = rep_ell[b,j,tau,2ell-m,:] * (-1)^(m-ell)
// Write-bound: 134 MB out, 2 MB in. Each block writes dense 1 KB records
// (all four ells) -> 16 KB contiguous per i'-iteration.

namespace {

typedef float f32x4 __attribute__((ext_vector_type(4)));

constexpr int Bn = 2;
constexpr int Nn = 256;
constexpr int TI = 8;    // i' rows per block
constexpr int TJ = 16;   // j' cols per block

// floats per (b,n) row, per ell: 32 taus * (2ell+1) m * 2 comps
__host__ __device__ constexpr int rf(int ell) { return 32 * (2 * ell + 1) * 2; }

// LDS float offsets for the 4 ell A-tiles (TI rows each)
constexpr int OFF0 = 0;
constexpr int OFF1 = OFF0 + TI * 64;    // 512
constexpr int OFF2 = OFF1 + TI * 192;   // 2048
constexpr int OFF3 = OFF2 + TI * 320;   // 4608
constexpr int LDSF = OFF3 + TI * 448;   // 8192 floats = 32 KB

__device__ __forceinline__ void stage(const float* __restrict__ src,
                                      float* __restrict__ dst, int nf, int tid) {
  const f32x4* s4 = reinterpret_cast<const f32x4*>(src);
  f32x4* d4 = reinterpret_cast<f32x4*>(dst);
  for (int k = tid; k < nf / 4; k += 256) d4[k] = s4[k];
}

// Load flipped+signed j-fragment for 2 taus (2f, 2f+1) into regs.
template <int ELL>
__device__ __forceinline__ void load_w(const float* __restrict__ rep, int b, int jg,
                                       int f, float (&w)[2][2 * ELL + 1][2]) {
  constexpr int M = 2 * ELL + 1;
  const float* g = rep + (size_t)(b * Nn + jg) * rf(ELL) + (2 * f) * (2 * M);
  #pragma unroll
  for (int t = 0; t < 2; ++t) {
    #pragma unroll
    for (int m = 0; m < M; ++m) {
      const float s = ((m ^ ELL) & 1) ? -1.0f : 1.0f;
      w[t][m][0] = g[t * 2 * M + (2 * ELL - m) * 2 + 0] * s;
      w[t][m][1] = g[t * 2 * M + (2 * ELL - m) * 2 + 1] * s;
    }
  }
}

// Complex dot for 2 taus at one (ell, i'); la points at lds A-row for tau=2f.
template <int ELL>
__device__ __forceinline__ f32x4 dot2(const float* __restrict__ la,
                                      const float (&w)[2][2 * ELL + 1][2]) {
  constexpr int M = 2 * ELL + 1;
  float r[2][2];
  #pragma unroll
  for (int t = 0; t < 2; ++t) { r[t][0] = 0.0f; r[t][1] = 0.0f; }
  #pragma unroll
  for (int t = 0; t < 2; ++t) {
    #pragma unroll
    for (int m = 0; m < M; ++m) {
      const float ar = la[t * 2 * M + 2 * m + 0];
      const float ai = la[t * 2 * M + 2 * m + 1];
      r[t][0] = fmaf(ar, w[t][m][0], r[t][0]);
      r[t][0] = fmaf(-ai, w[t][m][1], r[t][0]);
      r[t][1] = fmaf(ar, w[t][m][1], r[t][1]);
      r[t][1] = fmaf(ai, w[t][m][0], r[t][1]);
    }
  }
  f32x4 v;
  v.x = r[0][0]; v.y = r[0][1]; v.z = r[1][0]; v.w = r[1][1];
  return v;
}

__global__ __launch_bounds__(256) void dotmat_kernel(
    const float* __restrict__ r0, const float* __restrict__ r1,
    const float* __restrict__ r2, const float* __restrict__ r3,
    float* __restrict__ out) {
  __shared__ __align__(16) float lds[LDSF];
  const int b  = blockIdx.z;
  const int i0 = blockIdx.y * TI;
  const int j0 = blockIdx.x * TJ;
  const int tid = threadIdx.x;

  // stage A-tiles (all ells) into LDS, contiguous float4 copies
  stage(r0 + (size_t)(b * Nn + i0) * 64,  lds + OFF0, TI * 64,  tid);
  stage(r1 + (size_t)(b * Nn + i0) * 192, lds + OFF1, TI * 192, tid);
  stage(r2 + (size_t)(b * Nn + i0) * 320, lds + OFF2, TI * 320, tid);
  stage(r3 + (size_t)(b * Nn + i0) * 448, lds + OFF3, TI * 448, tid);

  const int f  = tid & 15;   // float4 index within 64-float ell segment (2 taus)
  const int jj = tid >> 4;   // j'

  // register-cache the flipped/signed j-fragments (all ells)
  float w0[2][1][2], w1[2][3][2], w2[2][5][2], w3[2][7][2];
  load_w<0>(r0, b, j0 + jj, f, w0);
  load_w<1>(r1, b, j0 + jj, f, w1);
  load_w<2>(r2, b, j0 + jj, f, w2);
  load_w<3>(r3, b, j0 + jj, f, w3);

  __syncthreads();

  for (int it = 0; it < TI; ++it) {
    float* op = out + (size_t)((b * Nn + i0 + it) * Nn + (j0 + jj)) * 256 + f * 4;
    const f32x4 v0 = dot2<0>(lds + OFF0 + it * 64  + (2 * f) * 2,  w0);
    const f32x4 v1 = dot2<1>(lds + OFF1 + it * 192 + (2 * f) * 6,  w1);
    const f32x4 v2 = dot2<2>(lds + OFF2 + it * 320 + (2 * f) * 10, w2);
    const f32x4 v3 = dot2<3>(lds + OFF3 + it * 448 + (2 * f) * 14, w3);
    __builtin_nontemporal_store(v0, reinterpret_cast<f32x4*>(op + 0 * 64));
    __builtin_nontemporal_store(v1, reinterpret_cast<f32x4*>(op + 1 * 64));
    __builtin_nontemporal_store(v2, reinterpret_cast<f32x4*>(op + 2 * 64));
    __builtin_nontemporal_store(v3, reinterpret_cast<f32x4*>(op + 3 * 64));
  }
}

}  // namespace

extern "C" void kernel_launch(void* const* d_in, const int* in_sizes, int n_in,
                              void* d_out, int out_size, void* d_ws, size_t ws_size,
                              hipStream_t stream) {
  (void)in_sizes; (void)n_in; (void)out_size; (void)d_ws; (void)ws_size;
  const float* r0 = (const float*)d_in[0];
  const float* r1 = (const float*)d_in[1];
  const float* r2 = (const float*)d_in[2];
  const float* r3 = (const float*)d_in[3];
  float* out = (float*)d_out;
  dim3 grid(Nn / TJ, Nn / TI, Bn);  // (16, 32, 2) = 1024 blocks
  dotmat_kernel<<<grid, 256, 0, stream>>>(r0, r1, r2, r3, out);
}